// Round 2
// baseline (123.029 us; speedup 1.0000x reference)
//
#include <hip/hip_runtime.h>

// Problem constants (fixed by the reference module)
#define B_ 16
#define L_ 2048
#define D_ 128
#define GROUP_ 16
#define NG_ (L_ / GROUP_)   // 128
#define LOG2E_ 1.44269504088896340736f

typedef float v2 __attribute__((ext_vector_type(2)));

// DPP-based butterfly add within each 16-lane row (full-rate VALU, no LDS).
template<int CTRL>
__device__ __forceinline__ float dpp_add(float v) {
    int x = __builtin_amdgcn_update_dpp(0, __float_as_int(v), CTRL, 0xF, 0xF, false);
    return v + __int_as_float(x);
}
__device__ __forceinline__ float row16_sum(float v) {
    v = dpp_add<0xB1>(v);   // quad_perm(1,0,3,2)  ~ xor 1
    v = dpp_add<0x4E>(v);   // quad_perm(2,3,0,1)  ~ xor 2
    v = dpp_add<0x141>(v);  // row_half_mirror     ~ xor 4
    v = dpp_add<0x140>(v);  // row_mirror          ~ xor 8
    return v;
}

// Full-rate-VALU reciprocal for d >= 1 (d finite): bit-trick guess + 2 Newton.
// rel err of guess ~5e-2 -> after 2 Newtons ~6e-6. Replaces v_rcp_f32
// (quarter-rate trans pipe) with 5 full-rate VALU ops; packs to v_pk_*.
__device__ __forceinline__ v2 fast_rcp2(v2 d) {
    v2 y;
    y.x = __int_as_float(0x7EF311C3 - __float_as_int(d.x));
    y.y = __int_as_float(0x7EF311C3 - __float_as_int(d.y));
    const v2 two = (v2){2.0f, 2.0f};
    y = y * __builtin_elementwise_fma(-d, y, two);
    y = y * __builtin_elementwise_fma(-d, y, two);
    return y;
}

// One block per (b,g) group. 256 threads = 16 rows x 16 lanes, 8 elems/thread.
//
// R11: rocprof showed both 256t(45us) and 512t(48us) configs pinned at
// VALUBusy~60-67% regardless of occupancy (33% vs 62%) -> throughput-bound
// on a per-SIMD pipe, not latency. Trans-pipe audit: 2 exp + 2 rcp per
// element-step = 268M quarter-rate ops ~ 27us of trans occupancy = the
// observed busy floor. This round: (a) reciprocals -> Newton on the
// full-rate VALU pipe (trans occupancy halved; only exp2 remains);
// (b) exp2 args clamped <=60 so d stays finite (saturated tanh == fp32
// reference exactly); (c) constants pinned via empty asm so the compiler
// can't sink their loads into the loop (VGPR 44/28 proved it was demoting).
__global__ __launch_bounds__(256, 4) void ncn_kernel(
    const float* __restrict__ x,       // (B, L, D)
    const int*   __restrict__ gt,      // (B, L) permutation
    const int*   __restrict__ ctxlens, // (B,)
    const float* __restrict__ W,       // (2D,)
    const float* __restrict__ nalpha,  // (2,)
    const float* __restrict__ ngamma,  // (2D,)
    const float* __restrict__ nbeta,   // (2D,)
    float* __restrict__ out)           // (2, B, L, D) concat: yi_out, ya_out
{
    const int blk = blockIdx.x;
    const int b   = blk >> 7;      // / NG_
    const int g   = blk & (NG_ - 1);
    const int tid = threadIdx.x;
    const int row = tid >> 4;      // 0..15 (token within group)
    const int rl  = tid & 15;      // 0..15 (lane within row)
    const int d0  = rl << 3;       // 8 d-elements per thread

    __shared__ float s_xj[2][D_];  // double-buffered broadcast row

    const float a1 = nalpha[0];
    const float a2 = nalpha[1];
    const float ca = -a1 * LOG2E_;        // u = ca*(xi + sim*xj) = -2*a1*log2e*T
    const float S  = -2.0f * a2 * LOG2E_; // za = S*xa, so exp2(za) direct
    const bool  selMin = (S < 0.0f);      // leaky-relu under sign flip

    // Per-chunk constants in registers (reused 16x), as packed v2 pairs.
    v2 Wi[4], Wj[4], G1S[4], B1S[4], G2[4], B2[4];
    {
        float4 wA = *(const float4*)(W + d0);
        float4 wB = *(const float4*)(W + d0 + 4);
        float4 vA = *(const float4*)(W + D_ + d0);
        float4 vB = *(const float4*)(W + D_ + d0 + 4);
        Wi[0] = (v2){wA.x, wA.y}; Wi[1] = (v2){wA.z, wA.w};
        Wi[2] = (v2){wB.x, wB.y}; Wi[3] = (v2){wB.z, wB.w};
        Wj[0] = (v2){vA.x, vA.y}; Wj[1] = (v2){vA.z, vA.w};
        Wj[2] = (v2){vB.x, vB.y}; Wj[3] = (v2){vB.z, vB.w};

        float4 g1A = *(const float4*)(ngamma + d0);
        float4 g1B = *(const float4*)(ngamma + d0 + 4);
        float4 g2A = *(const float4*)(ngamma + D_ + d0);
        float4 g2B = *(const float4*)(ngamma + D_ + d0 + 4);
        float4 b1A = *(const float4*)(nbeta + d0);
        float4 b1B = *(const float4*)(nbeta + d0 + 4);
        float4 b2A = *(const float4*)(nbeta + D_ + d0);
        float4 b2B = *(const float4*)(nbeta + D_ + d0 + 4);

        v2 g1v[4] = {(v2){g1A.x,g1A.y},(v2){g1A.z,g1A.w},(v2){g1B.x,g1B.y},(v2){g1B.z,g1B.w}};
        v2 b1v[4] = {(v2){b1A.x,b1A.y},(v2){b1A.z,b1A.w},(v2){b1B.x,b1B.y},(v2){b1B.z,b1B.w}};
        v2 g2v[4] = {(v2){g2A.x,g2A.y},(v2){g2A.z,g2A.w},(v2){g2B.x,g2B.y},(v2){g2B.z,g2B.w}};
        v2 b2v[4] = {(v2){b2A.x,b2A.y},(v2){b2A.z,b2A.w},(v2){b2B.x,b2B.y},(v2){b2B.z,b2B.w}};
#pragma unroll
        for (int k = 0; k < 4; ++k) {
            G1S[k] = (S * 2.0f) * g1v[k];        // S*(2*g1)
            B1S[k] = S * (b1v[k] - g1v[k]);      // S*(b1-g1)
            G2[k]  = 2.0f * g2v[k];
            B2[k]  = b2v[k] - g2v[k];
        }
    }
    // Opaque defs: the compiler may not rematerialize these as per-step
    // global reloads (R9/R10 VGPR counts proved it was doing exactly that).
#pragma unroll
    for (int k = 0; k < 4; ++k) {
        asm volatile("" : "+v"(Wi[k]), "+v"(Wj[k]), "+v"(G1S[k]),
                          "+v"(B1S[k]), "+v"(G2[k]), "+v"(B2[k]));
    }

    // Gather this row's token
    const int l   = g * GROUP_ + row;
    const int tok = gt[b * L_ + l];
    const float* xp = x + ((size_t)(b * L_ + tok)) * D_ + d0;

    v2 xi[4], za[4];
    {
        float4 xA = *(const float4*)xp;
        float4 xB = *(const float4*)(xp + 4);
        xi[0] = (v2){xA.x, xA.y}; xi[1] = (v2){xA.z, xA.w};
        xi[2] = (v2){xB.x, xB.y}; xi[3] = (v2){xB.z, xB.w};
    }
#pragma unroll
    for (int k = 0; k < 4; ++k) za[k] = (v2){0.0f, 0.0f};

    // Row 0 publishes its initial xi into buffer 0
    if (row == 0) {
        *(v2*)&s_xj[0][d0]     = xi[0];
        *(v2*)&s_xj[0][d0 + 2] = xi[1];
        *(v2*)&s_xj[0][d0 + 4] = xi[2];
        *(v2*)&s_xj[0][d0 + 6] = xi[3];
    }
    __syncthreads();

    for (int j = 0; j < GROUP_; ++j) {
        const int p = j & 1;

        v2 xjv[4];
        {
            float4 tA = *(const float4*)&s_xj[p][d0];
            float4 tB = *(const float4*)&s_xj[p][d0 + 4];
            xjv[0] = (v2){tA.x, tA.y}; xjv[1] = (v2){tA.z, tA.w};
            xjv[2] = (v2){tB.x, tB.y}; xjv[3] = (v2){tB.z, tB.w};
        }

        // sim = dot(xi,Wi) + dot(xj,Wj): packed FMAs, one DPP reduce.
        v2 sv = (v2){0.0f, 0.0f};
#pragma unroll
        for (int k = 0; k < 4; ++k) sv = __builtin_elementwise_fma(xi[k],  Wi[k], sv);
#pragma unroll
        for (int k = 0; k < 4; ++k) sv = __builtin_elementwise_fma(xjv[k], Wj[k], sv);
        const float sim = row16_sum(sv.x + sv.y);
        const v2 simv  = (v2){sim, sim};
        const v2 cav   = (v2){ca, ca};
        const v2 onev  = (v2){1.0f, 1.0f};
        const v2 leak  = (v2){0.01f, 0.01f};
        const v2 clampv = (v2){60.0f, 60.0f};   // keeps d finite; tanh saturated == ref

#pragma unroll
        for (int k = 0; k < 4; ++k) {
            // u = ca * (xi + sim*xj) = -2*a1*log2e * T
            v2 T2 = __builtin_elementwise_fma(simv, xjv[k], xi[k]);
            v2 u  = __builtin_elementwise_min(cav * T2, clampv);
            v2 e1 = (v2){__builtin_amdgcn_exp2f(u.x), __builtin_amdgcn_exp2f(u.y)};
            v2 r1 = fast_rcp2(e1 + onev);                            // VALU, not trans
            v2 tnS = __builtin_elementwise_fma(G1S[k], r1, B1S[k]);  // S*(g1*tanh+b1)
            v2 alt = tnS * leak;
            v2 FvS = selMin ? __builtin_elementwise_min(tnS, alt)
                            : __builtin_elementwise_max(tnS, alt);
            za[k] += FvS;                                            // za = S * xa
            v2 zc = __builtin_elementwise_min(za[k], clampv);
            v2 e2 = (v2){__builtin_amdgcn_exp2f(zc.x), __builtin_amdgcn_exp2f(zc.y)};
            v2 r2 = fast_rcp2(e2 + onev);                            // VALU, not trans
            xi[k] = __builtin_elementwise_fma(G2[k], r2, xi[k] + B2[k]); // xi += g2*tanh+b2
        }

        // Next step's broadcaster writes the OTHER buffer; the single
        // barrier orders both visibility and WAR reuse.
        if (j + 1 < GROUP_ && row == j + 1) {
            *(v2*)&s_xj[p ^ 1][d0]     = xi[0];
            *(v2*)&s_xj[p ^ 1][d0 + 2] = xi[1];
            *(v2*)&s_xj[p ^ 1][d0 + 4] = xi[2];
            *(v2*)&s_xj[p ^ 1][d0 + 6] = xi[3];
        }
        __syncthreads();
    }

    // Recover xa = za / S
    const float invS = 1.0f / S;
    const v2 invSv = (v2){invS, invS};
    v2 xa[4];
#pragma unroll
    for (int k = 0; k < 4; ++k) xa[k] = za[k] * invSv;

    const bool valid = (g * GROUP_) < ctxlens[b];
    if (!valid) {
#pragma unroll
        for (int k = 0; k < 4; ++k) { xi[k] = (v2){0,0}; xa[k] = (v2){0,0}; }
    }

    // Scatter back through the permutation (bijective -> every out elem written)
    float* o1 = out + ((size_t)(b * L_ + tok)) * D_ + d0;
    float* o2 = o1 + (size_t)B_ * L_ * D_;
    float4 s1A = {xi[0].x, xi[0].y, xi[1].x, xi[1].y};
    float4 s1B = {xi[2].x, xi[2].y, xi[3].x, xi[3].y};
    float4 s2A = {xa[0].x, xa[0].y, xa[1].x, xa[1].y};
    float4 s2B = {xa[2].x, xa[2].y, xa[3].x, xa[3].y};
    *(float4*)o1       = s1A;
    *(float4*)(o1 + 4) = s1B;
    *(float4*)o2       = s2A;
    *(float4*)(o2 + 4) = s2B;
}

extern "C" void kernel_launch(void* const* d_in, const int* in_sizes, int n_in,
                              void* d_out, int out_size, void* d_ws, size_t ws_size,
                              hipStream_t stream) {
    const float* x  = (const float*)d_in[0];
    const int*   gt = (const int*)d_in[1];
    const int*   cl = (const int*)d_in[2];
    const float* W  = (const float*)d_in[3];
    const float* na = (const float*)d_in[4];
    const float* ng = (const float*)d_in[5];
    const float* nb = (const float*)d_in[6];
    float* out = (float*)d_out;

    ncn_kernel<<<B_ * NG_, 256, 0, stream>>>(x, gt, cl, W, na, ng, nb, out);
}